// Round 1
// baseline (1035.540 us; speedup 1.0000x reference)
//
#include <hip/hip_runtime.h>

#define BB 1024
#define TT 200
#define DD 64
#define HH 64

__device__ __forceinline__ float sigmoidf_(float x) { return 1.0f / (1.0f + __expf(-x)); }
__device__ __forceinline__ float dicef_(float x, float m, float v) {
    return x * sigmoidf_((x - m) * rsqrtf(v + 1e-9f));
}

// ---------------------------------------------------------------------------
// k_prep: target_embed (B,64) and other_info (B,36) = [dense(4), tab0(16), tab1(16)]
// ---------------------------------------------------------------------------
__global__ void k_prep(const float* __restrict__ dense, const int* __restrict__ sparse,
                       const int* __restrict__ item_idx, const float* __restrict__ table,
                       const float* __restrict__ other_tables,
                       float* __restrict__ target, float* __restrict__ other) {
    int b = blockIdx.x, l = threadIdx.x;  // 64 threads
    target[b * 64 + l] = table[(size_t)item_idx[b] * 64 + l];
    if (l < 4) other[b * 36 + l] = dense[b * 4 + l];
    else if (l < 20) other[b * 36 + l] = other_tables[(size_t)sparse[b * 2 + 0] * 16 + (l - 4)];
    else if (l < 36) other[b * 36 + l] = other_tables[1000 * 16 + (size_t)sparse[b * 2 + 1] * 16 + (l - 20)];
}

// ---------------------------------------------------------------------------
// k_scan: masked (AU)GRU scan. 4 batch rows per block, 4 waves.
//   Weights register-resident, k-split across waves (wave w owns k in [16w,16w+16)).
//   Per step: partial dots -> LDS reduce -> gates. 2 barriers/step.
// GATHER=1: x comes from item_table[seq_idx] with 1-step prefetch (GRU1).
// AUG=1: z *= scores, writes hfinal only (AUGRU). Else writes hout (T,B,64).
// ---------------------------------------------------------------------------
template <int GATHER, int AUG>
__global__ __launch_bounds__(256) void k_scan(
    const float* __restrict__ xin,      // (T,B,64) when !GATHER
    const int* __restrict__ seq_idx,    // (B,T) when GATHER
    const float* __restrict__ table,    // (1M,64) when GATHER
    const float* __restrict__ W,        // (64,192)
    const float* __restrict__ U,        // (64,192)
    const float* __restrict__ bias,     // (192,)
    const int* __restrict__ hist_len,   // (B,)
    const float* __restrict__ scores,   // (B,T) when AUG
    float* __restrict__ hout,           // (T,B,64) when !AUG
    float* __restrict__ hfinal)         // (B,64) when AUG
{
    __shared__ float P[4][4][4][64];  // [kchunk][row][{z,r,xh,hh}][col]
    __shared__ float x_lds[4][64];
    __shared__ float h_lds[4][64];

    const int tid = threadIdx.x;
    const int w = tid >> 6;   // wave id: k-chunk in phase A, row in phase C
    const int l = tid & 63;
    const int r0 = blockIdx.x * 4;
    const int myrow = r0 + w;

    // register-resident weight slices for k in [16w, 16w+16)
    float Wz[16], Wr[16], Wh[16], Uz[16], Ur[16], Uh[16];
#pragma unroll
    for (int kk = 0; kk < 16; ++kk) {
        int k = (w << 4) + kk;
        Wz[kk] = W[k * 192 + l];
        Wr[kk] = W[k * 192 + 64 + l];
        Wh[kk] = W[k * 192 + 128 + l];
        Uz[kk] = U[k * 192 + l];
        Ur[kk] = U[k * 192 + 64 + l];
        Uh[kk] = U[k * 192 + 128 + l];
    }
    const float bz = bias[l], br = bias[64 + l], bh = bias[128 + l];
    const int mylen = hist_len[myrow];
    float h_reg = 0.f;

    h_lds[w][l] = 0.f;
    if (GATHER) {
        int idx0 = seq_idx[(size_t)myrow * TT];
        x_lds[w][l] = table[(size_t)idx0 * 64 + l];
    } else {
        x_lds[w][l] = xin[(size_t)myrow * 64 + l];
    }
    __syncthreads();

    for (int t = 0; t < TT; ++t) {
        // prefetch next x (covers HBM/L3 gather latency with a full step of compute)
        float xnext = 0.f;
        if (t + 1 < TT) {
            if (GATHER) {
                int idx = seq_idx[(size_t)myrow * TT + (t + 1)];
                xnext = table[(size_t)idx * 64 + l];
            } else {
                xnext = xin[((size_t)(t + 1) * BB + myrow) * 64 + l];
            }
        }

        // phase A: partial dots over this wave's k-chunk, all 4 rows
        float pz[4] = {0.f, 0.f, 0.f, 0.f}, pr[4] = {0.f, 0.f, 0.f, 0.f};
        float pxh[4] = {0.f, 0.f, 0.f, 0.f}, phh[4] = {0.f, 0.f, 0.f, 0.f};
#pragma unroll
        for (int kk = 0; kk < 16; kk += 2) {
            const int k = (w << 4) + kk;
#pragma unroll
            for (int rr = 0; rr < 4; ++rr) {
                float2 xv = *(const float2*)&x_lds[rr][k];  // broadcast
                float2 hv = *(const float2*)&h_lds[rr][k];  // broadcast
                pz[rr] += xv.x * Wz[kk] + xv.y * Wz[kk + 1] + hv.x * Uz[kk] + hv.y * Uz[kk + 1];
                pr[rr] += xv.x * Wr[kk] + xv.y * Wr[kk + 1] + hv.x * Ur[kk] + hv.y * Ur[kk + 1];
                pxh[rr] += xv.x * Wh[kk] + xv.y * Wh[kk + 1];
                phh[rr] += hv.x * Uh[kk] + hv.y * Uh[kk + 1];
            }
        }
#pragma unroll
        for (int rr = 0; rr < 4; ++rr) {
            P[w][rr][0][l] = pz[rr];
            P[w][rr][1][l] = pr[rr];
            P[w][rr][2][l] = pxh[rr];
            P[w][rr][3][l] = phh[rr];
        }
        __syncthreads();  // bar1: phase-A reads + P writes complete

        x_lds[w][l] = xnext;  // safe: all x_lds reads for step t are done

        // phase C: this thread owns (row = r0+w, col l)
        float az = P[0][w][0][l] + P[1][w][0][l] + P[2][w][0][l] + P[3][w][0][l];
        float ar = P[0][w][1][l] + P[1][w][1][l] + P[2][w][1][l] + P[3][w][1][l];
        float axh = P[0][w][2][l] + P[1][w][2][l] + P[2][w][2][l] + P[3][w][2][l];
        float ahh = P[0][w][3][l] + P[1][w][3][l] + P[2][w][3][l] + P[3][w][3][l];

        float zg = sigmoidf_(az + bz);
        float rg = sigmoidf_(ar + br);
        float hh = tanhf(axh + bh + rg * ahh);
        if (AUG) zg *= scores[(size_t)myrow * TT + t];
        float hn = (1.f - zg) * h_reg + zg * hh;
        h_reg = (t < mylen) ? hn : h_reg;
        h_lds[w][l] = h_reg;
        if (!AUG) hout[((size_t)t * BB + myrow) * 64 + l] = h_reg;
        __syncthreads();  // bar2: P reads done; x_lds/h_lds updates visible
    }
    if (AUG) hfinal[(size_t)myrow * 64 + l] = h_reg;
}

// ---------------------------------------------------------------------------
// k_att: per-(b,t) attention MLP 256->64->16->1, masked logits to (B,T).
//   8 rows per wave, W1^T staged in padded LDS (2-way bank aliasing = free).
// ---------------------------------------------------------------------------
__global__ __launch_bounds__(256) void k_att(
    const float* __restrict__ target, const float* __restrict__ seq_h,
    const float* __restrict__ W1, const float* __restrict__ b1,
    const float* __restrict__ W2, const float* __restrict__ b2,
    const float* __restrict__ W3, const float* __restrict__ b3,
    const int* __restrict__ hist_len, float* __restrict__ logits)
{
    __shared__ float W1t[64][258];     // transposed (256,64) -> [c][k], pad 258
    __shared__ float W2L[64][16];
    __shared__ float feats[4][8][256]; // per-wave slab
    __shared__ float a1s[4][8][64];

    const int tid = threadIdx.x;
    const int wv = tid >> 6, l = tid & 63;

    for (int i = tid; i < 256 * 64; i += 256) {
        int k = i >> 6, c = i & 63;
        W1t[c][k] = W1[i];
    }
    for (int i = tid; i < 64 * 16; i += 256) ((float*)W2L)[i] = W2[i];
    const float b1r = b1[l];
    const float b2r = b2[l & 15];
    const float w3r = W3[l & 15];
    const float b3r = b3[0];
    __syncthreads();

    const int ntile = (BB * TT) / 8;
    for (int tile = blockIdx.x * 4 + wv; tile < ntile; tile += gridDim.x * 4) {
        const int rowb = tile * 8;
        int bs[8], ts[8];
#pragma unroll
        for (int i = 0; i < 8; ++i) {
            int row = rowb + i;
            int b = row / TT, t = row - b * TT;
            bs[i] = b; ts[i] = t;
            float q = target[b * 64 + l];
            float h = seq_h[((size_t)t * BB + b) * 64 + l];
            feats[wv][i][l] = q;
            feats[wv][i][64 + l] = h;
            feats[wv][i][128 + l] = q - h;
            feats[wv][i][192 + l] = q * h;
        }
        // layer 1: output channel c = l, for 8 rows
        float acc[8] = {0.f, 0.f, 0.f, 0.f, 0.f, 0.f, 0.f, 0.f};
        for (int k = 0; k < 256; k += 2) {
            float2 wv2 = *(const float2*)&W1t[l][k];
#pragma unroll
            for (int i = 0; i < 8; ++i) {
                float2 f = *(const float2*)&feats[wv][i][k];
                acc[i] += f.x * wv2.x + f.y * wv2.y;
            }
        }
#pragma unroll
        for (int i = 0; i < 8; ++i) {
            float v = acc[i] + b1r;
            a1s[wv][i][l] = (v > 0.f) ? v : 0.25f * v;
        }
        // layers 2 (64->16, k split 4 ways across lane groups) + 3 (16->1)
        const int j = l & 15, kq = l >> 4;
#pragma unroll
        for (int i = 0; i < 8; ++i) {
            float a2 = 0.f;
#pragma unroll
            for (int kk = 0; kk < 16; ++kk)
                a2 += a1s[wv][i][kq * 16 + kk] * W2L[kq * 16 + kk][j];
            a2 += __shfl_xor(a2, 16);
            a2 += __shfl_xor(a2, 32);
            a2 += b2r;
            a2 = (a2 > 0.f) ? a2 : 0.25f * a2;
            float part = a2 * w3r;  // 64-lane sum = 4 * sum_j
#pragma unroll
            for (int m = 1; m < 64; m <<= 1) part += __shfl_xor(part, m);
            if (l == 0) {
                float logit = 0.25f * part + b3r;
                int b = bs[i], t = ts[i];
                logit = (t < hist_len[b]) ? logit : -1e9f;
                logits[(size_t)b * TT + t] = logit;
            }
        }
    }
}

// ---------------------------------------------------------------------------
// k_softmax: in-place masked softmax over T per batch row. 1 wave per row.
// ---------------------------------------------------------------------------
__global__ void k_softmax(float* __restrict__ scores) {
    int b = blockIdx.x, l = threadIdx.x;  // 64 threads
    float v[4];
#pragma unroll
    for (int j = 0; j < 4; ++j) {
        int t = l + 64 * j;
        v[j] = (t < TT) ? scores[(size_t)b * TT + t] : -1e30f;
    }
    float m = fmaxf(fmaxf(v[0], v[1]), fmaxf(v[2], v[3]));
#pragma unroll
    for (int s = 1; s < 64; s <<= 1) m = fmaxf(m, __shfl_xor(m, s));
    float e[4], sum = 0.f;
#pragma unroll
    for (int j = 0; j < 4; ++j) { e[j] = __expf(v[j] - m); sum += e[j]; }
#pragma unroll
    for (int s = 1; s < 64; s <<= 1) sum += __shfl_xor(sum, s);
    float inv = 1.f / sum;
#pragma unroll
    for (int j = 0; j < 4; ++j) {
        int t = l + 64 * j;
        if (t < TT) scores[(size_t)b * TT + t] = e[j] * inv;
    }
}

// ---------------------------------------------------------------------------
// FFN kernels (tiny). Dice stats = per-feature mean/var over batch.
// ---------------------------------------------------------------------------
__global__ __launch_bounds__(256) void k_fc1(const float* __restrict__ fin,
                                             const float* __restrict__ tgt,
                                             const float* __restrict__ oth,
                                             const float* __restrict__ Wt,
                                             const float* __restrict__ bvec,
                                             float* __restrict__ fout) {
    __shared__ float z0[164];
    int b = blockIdx.x, tid = threadIdx.x;
    if (tid < 64) z0[tid] = fin[b * 64 + tid];
    else if (tid < 128) z0[tid] = tgt[b * 64 + tid - 64];
    else if (tid < 164) z0[tid] = oth[b * 36 + tid - 128];
    __syncthreads();
    float acc = bvec[tid];
#pragma unroll 4
    for (int k = 0; k < 164; ++k) acc += z0[k] * Wt[k * 256 + tid];
    fout[(size_t)b * 256 + tid] = acc;
}

template <int F>
__global__ __launch_bounds__(256) void k_stats(const float* __restrict__ x, float* __restrict__ stat) {
    int c = blockIdx.x, tid = threadIdx.x;
    float s = 0.f, sq = 0.f;
    for (int i = tid; i < BB; i += 256) {
        float v = x[(size_t)i * F + c];
        s += v; sq += v * v;
    }
#pragma unroll
    for (int m = 1; m < 64; m <<= 1) { s += __shfl_xor(s, m); sq += __shfl_xor(sq, m); }
    __shared__ float rs[4], rq[4];
    if ((tid & 63) == 0) { rs[tid >> 6] = s; rq[tid >> 6] = sq; }
    __syncthreads();
    if (tid == 0) {
        float S = rs[0] + rs[1] + rs[2] + rs[3];
        float Q = rq[0] + rq[1] + rq[2] + rq[3];
        float mean = S * (1.f / BB);
        float var = Q * (1.f / BB) - mean * mean;
        stat[c] = mean;
        stat[F + c] = var;
    }
}

__global__ __launch_bounds__(256) void k_fc2(const float* __restrict__ f1,
                                             const float* __restrict__ st1,
                                             const float* __restrict__ Wt,
                                             const float* __restrict__ bvec,
                                             float* __restrict__ f2) {
    __shared__ float z[256];
    int b = blockIdx.x, tid = threadIdx.x;
    float x = f1[(size_t)b * 256 + tid];
    z[tid] = dicef_(x, st1[tid], st1[256 + tid]);
    __syncthreads();
    if (tid < 128) {
        float acc = bvec[tid];
#pragma unroll 4
        for (int k = 0; k < 256; ++k) acc += z[k] * Wt[k * 128 + tid];
        f2[(size_t)b * 128 + tid] = acc;
    }
}

__global__ __launch_bounds__(128) void k_fc3(const float* __restrict__ f2,
                                             const float* __restrict__ st2,
                                             const float* __restrict__ Wt,
                                             const float* __restrict__ bvec,
                                             float* __restrict__ f3) {
    __shared__ float z[128];
    int b = blockIdx.x, tid = threadIdx.x;
    float x = f2[(size_t)b * 128 + tid];
    z[tid] = dicef_(x, st2[tid], st2[128 + tid]);
    __syncthreads();
    if (tid < 64) {
        float acc = bvec[tid];
#pragma unroll 4
        for (int k = 0; k < 128; ++k) acc += z[k] * Wt[k * 64 + tid];
        f3[(size_t)b * 64 + tid] = acc;
    }
}

__global__ void k_out(const float* __restrict__ f3, const float* __restrict__ st3,
                      const float* __restrict__ outW, const float* __restrict__ outb,
                      float* __restrict__ out) {
    int b = blockIdx.x, l = threadIdx.x;  // 64 threads
    float x = f3[(size_t)b * 64 + l];
    float z = dicef_(x, st3[l], st3[64 + l]);
    float p = z * outW[l];
#pragma unroll
    for (int m = 1; m < 64; m <<= 1) p += __shfl_xor(p, m);
    if (l == 0) out[b] = sigmoidf_(p + outb[0]);
}

// ---------------------------------------------------------------------------
extern "C" void kernel_launch(void* const* d_in, const int* in_sizes, int n_in,
                              void* d_out, int out_size, void* d_ws, size_t ws_size,
                              hipStream_t stream) {
    const float* dense      = (const float*)d_in[0];
    const int*   sparse     = (const int*)d_in[1];
    const int*   seq_idx    = (const int*)d_in[2];
    const int*   item_idx   = (const int*)d_in[3];
    const int*   hist_len   = (const int*)d_in[4];
    const float* item_table = (const float*)d_in[5];
    const float* other_tab  = (const float*)d_in[6];
    const float* gru_W = (const float*)d_in[7];
    const float* gru_U = (const float*)d_in[8];
    const float* gru_b = (const float*)d_in[9];
    const float* aug_W = (const float*)d_in[10];
    const float* aug_U = (const float*)d_in[11];
    const float* aug_b = (const float*)d_in[12];
    const float* att_W1 = (const float*)d_in[13];
    const float* att_b1 = (const float*)d_in[14];
    const float* att_W2 = (const float*)d_in[15];
    const float* att_b2 = (const float*)d_in[16];
    const float* att_W3 = (const float*)d_in[17];
    const float* att_b3 = (const float*)d_in[18];
    const float* ffn_W1 = (const float*)d_in[19];
    const float* ffn_b1 = (const float*)d_in[20];
    const float* ffn_W2 = (const float*)d_in[21];
    const float* ffn_b2 = (const float*)d_in[22];
    const float* ffn_W3 = (const float*)d_in[23];
    const float* ffn_b3 = (const float*)d_in[24];
    const float* out_W  = (const float*)d_in[25];
    const float* out_b  = (const float*)d_in[26];

    float* wsf = (float*)d_ws;
    // workspace layout (floats); total ~13.94M floats = 55.8 MB
    float* seq_h  = wsf;                       // T*B*64 = 13,107,200
    float* scores = wsf + 13107200;            // B*T    =    204,800
    float* target = wsf + 13312000;            // B*64   =     65,536
    float* other  = wsf + 13377536;            // B*36   =     36,864
    float* finals = wsf + 13414400;            // B*64   =     65,536
    float* f1     = wsf + 13479936;            // B*256  =    262,144
    float* f2     = wsf + 13742080;            // B*128  =    131,072
    float* f3     = wsf + 13873152;            // B*64   =     65,536
    float* st1    = wsf + 13938688;            // 512
    float* st2    = wsf + 13939200;            // 256
    float* st3    = wsf + 13939456;            // 128

    float* dout = (float*)d_out;

    k_prep<<<BB, 64, 0, stream>>>(dense, sparse, item_idx, item_table, other_tab, target, other);

    // GRU1: fused gather, writes seq_h (T,B,64)
    k_scan<1, 0><<<BB / 4, 256, 0, stream>>>(nullptr, seq_idx, item_table,
                                             gru_W, gru_U, gru_b, hist_len,
                                             nullptr, seq_h, nullptr);

    k_att<<<256, 256, 0, stream>>>(target, seq_h, att_W1, att_b1, att_W2, att_b2,
                                   att_W3, att_b3, hist_len, scores);
    k_softmax<<<BB, 64, 0, stream>>>(scores);

    // AUGRU: x = seq_h, attention-scaled update gate, writes final state
    k_scan<0, 1><<<BB / 4, 256, 0, stream>>>(seq_h, nullptr, nullptr,
                                             aug_W, aug_U, aug_b, hist_len,
                                             scores, nullptr, finals);

    k_fc1<<<BB, 256, 0, stream>>>(finals, target, other, ffn_W1, ffn_b1, f1);
    k_stats<256><<<256, 256, 0, stream>>>(f1, st1);
    k_fc2<<<BB, 256, 0, stream>>>(f1, st1, ffn_W2, ffn_b2, f2);
    k_stats<128><<<128, 256, 0, stream>>>(f2, st2);
    k_fc3<<<BB, 128, 0, stream>>>(f2, st2, ffn_W3, ffn_b3, f3);
    k_stats<64><<<64, 256, 0, stream>>>(f3, st3);
    k_out<<<BB, 64, 0, stream>>>(f3, st3, out_W, out_b, dout);
}

// Round 2
// 771.272 us; speedup vs baseline: 1.3426x; 1.3426x over previous
//
#include <hip/hip_runtime.h>

#define BB 1024
#define TT 200

typedef __attribute__((ext_vector_type(8))) short short8;
typedef __attribute__((ext_vector_type(4))) float f32x4;

__device__ __forceinline__ float sigmoidf_(float x) { return __fdividef(1.0f, 1.0f + __expf(-x)); }
__device__ __forceinline__ float tanh_fast(float x) {
    x = fminf(15.f, fmaxf(-15.f, x));
    float e = __expf(-2.f * x);
    return __fdividef(1.f - e, 1.f + e);
}
__device__ __forceinline__ float dicef_(float x, float m, float v) {
    return x * sigmoidf_((x - m) * rsqrtf(v + 1e-9f));
}
__device__ __forceinline__ unsigned short f2bf(float f) {
    unsigned u = __float_as_uint(f);
    unsigned r = u + 0x7fffu + ((u >> 16) & 1u);
    return (unsigned short)(r >> 16);
}
__device__ __forceinline__ float bf2f(unsigned short h) {
    return __uint_as_float(((unsigned)h) << 16);
}

// ---------------------------------------------------------------------------
// k_prep: target_embed (B,64) f32 and other_info (B,36)
// ---------------------------------------------------------------------------
__global__ void k_prep(const float* __restrict__ dense, const int* __restrict__ sparse,
                       const int* __restrict__ item_idx, const float* __restrict__ table,
                       const float* __restrict__ other_tables,
                       float* __restrict__ target, float* __restrict__ other) {
    int b = blockIdx.x, l = threadIdx.x;  // 64 threads
    target[b * 64 + l] = table[(size_t)item_idx[b] * 64 + l];
    if (l < 4) other[b * 36 + l] = dense[b * 4 + l];
    else if (l < 20) other[b * 36 + l] = other_tables[(size_t)sparse[b * 2 + 0] * 16 + (l - 4)];
    else if (l < 36) other[b * 36 + l] = other_tables[1000 * 16 + (size_t)sparse[b * 2 + 1] * 16 + (l - 20)];
}

// ---------------------------------------------------------------------------
// k_xw: XW = X @ W + bias, output bf16 (M,192).  X is either a gather from
// the f32 item table (GATHER=1) or a bf16 matrix (M,64) (GATHER=0).
// bf16 MFMA 16x16x32. One 16-row tile per wave iteration, 12 n-tiles, 2 k-chunks.
// A frag: lane l holds A[l%16][c*32 + (l/16)*8 + j].  B frag: B[k][l%16], same k set.
// C frag: row = (l/16)*4 + j, col = l%16.
// ---------------------------------------------------------------------------
template <int GATHER>
__global__ __launch_bounds__(256, 1) void k_xw(
    const int* __restrict__ idx, const float* __restrict__ tablef,
    const unsigned short* __restrict__ Abf,
    const float* __restrict__ W, const float* __restrict__ bias,
    unsigned short* __restrict__ out, int Mtiles, int tilestride)
{
    const int l = threadIdx.x & 63;
    const int wv = threadIdx.x >> 6;
    const int lg = l >> 4;   // lane group 0..3
    const int li = l & 15;

    // register-resident B fragments (whole W: 64x192 as bf16) + bias
    short8 bfr[12][2];
    float bn[12];
#pragma unroll
    for (int nt = 0; nt < 12; ++nt) {
        bn[nt] = bias[nt * 16 + li];
#pragma unroll
        for (int c = 0; c < 2; ++c) {
#pragma unroll
            for (int j = 0; j < 8; ++j) {
                int k = c * 32 + lg * 8 + j;
                bfr[nt][c][j] = (short)f2bf(W[k * 192 + nt * 16 + li]);
            }
        }
    }

    for (int tile = blockIdx.x * 4 + wv; tile < Mtiles; tile += tilestride) {
        short8 a[2];
        if (GATHER) {
            long row = (long)tile * 16 + li;
            long id = idx[row];
            const float* tp = tablef + id * 64 + lg * 8;
#pragma unroll
            for (int c = 0; c < 2; ++c) {
                f32x4 v0 = *(const f32x4*)(tp + c * 32);
                f32x4 v1 = *(const f32x4*)(tp + c * 32 + 4);
#pragma unroll
                for (int j = 0; j < 4; ++j) {
                    a[c][j] = (short)f2bf(v0[j]);
                    a[c][4 + j] = (short)f2bf(v1[j]);
                }
            }
        } else {
            long row = (long)tile * 16 + li;
#pragma unroll
            for (int c = 0; c < 2; ++c)
                a[c] = *(const short8*)(Abf + row * 64 + c * 32 + lg * 8);
        }

        f32x4 acc[12];
#pragma unroll
        for (int nt = 0; nt < 12; ++nt) acc[nt] = (f32x4){0.f, 0.f, 0.f, 0.f};
#pragma unroll
        for (int c = 0; c < 2; ++c)
#pragma unroll
            for (int nt = 0; nt < 12; ++nt)
                acc[nt] = __builtin_amdgcn_mfma_f32_16x16x32_bf16(a[c], bfr[nt][c], acc[nt], 0, 0, 0);

#pragma unroll
        for (int nt = 0; nt < 12; ++nt)
#pragma unroll
            for (int j = 0; j < 4; ++j) {
                long row = (long)tile * 16 + lg * 4 + j;
                out[row * 192 + nt * 16 + li] = f2bf(acc[nt][j] + bn[nt]);
            }
    }
}

// ---------------------------------------------------------------------------
// k_scan2: recurrent part only (h@U), x@W+b precomputed in xw (bf16, (B,T,192)).
// One wave per batch row; U fully register-resident (192 VGPR); h broadcast
// via uniform-address ds_read_b128; NO barriers (waves fully independent).
// AUG=1: z *= scores, writes hfinal f32 (B,64).  AUG=0: writes hout bf16 (B,T,64).
// ---------------------------------------------------------------------------
template <int AUG>
__global__ __launch_bounds__(256, 1) void k_scan2(
    const unsigned short* __restrict__ xw,
    const float* __restrict__ U,
    const int* __restrict__ hist_len,
    const float* __restrict__ scores,
    unsigned short* __restrict__ hout,
    float* __restrict__ hfinal)
{
    __shared__ float h_lds[4][64];
    const int w = threadIdx.x >> 6, l = threadIdx.x & 63;
    const int b = blockIdx.x * 4 + w;

    float Uz[64], Ur[64], Uh[64];
#pragma unroll
    for (int k = 0; k < 64; ++k) {
        Uz[k] = U[k * 192 + l];
        Ur[k] = U[k * 192 + 64 + l];
        Uh[k] = U[k * 192 + 128 + l];
    }
    const int mylen = hist_len[b];
    const unsigned short* xwr = xw + (size_t)b * TT * 192;
    const float* scr = scores + (size_t)b * TT;
    unsigned short* hor = hout + (size_t)b * TT * 64;

    float h = 0.f;
    h_lds[w][l] = 0.f;
    asm volatile("" ::: "memory");

    // software prefetch of step-t inputs one step ahead
    unsigned short nz = xwr[l], nr = xwr[64 + l], nh = xwr[128 + l];
    float ns = AUG ? scr[0] : 0.f;

    for (int t = 0; t < TT; ++t) {
        const unsigned short cz = nz, cr = nr, ch = nh;
        const float cs = ns;
        if (t + 1 < TT) {
            const unsigned short* p = xwr + (size_t)(t + 1) * 192;
            nz = p[l]; nr = p[64 + l]; nh = p[128 + l];
            if (AUG) ns = scr[t + 1];
        }

        float az = 0.f, ar = 0.f, ah = 0.f;
        const float4* h4 = (const float4*)(&h_lds[w][0]);
#pragma unroll
        for (int kc = 0; kc < 16; ++kc) {
            float4 hv = h4[kc];
            az += hv.x * Uz[4*kc] + hv.y * Uz[4*kc+1] + hv.z * Uz[4*kc+2] + hv.w * Uz[4*kc+3];
            ar += hv.x * Ur[4*kc] + hv.y * Ur[4*kc+1] + hv.z * Ur[4*kc+2] + hv.w * Ur[4*kc+3];
            ah += hv.x * Uh[4*kc] + hv.y * Uh[4*kc+1] + hv.z * Uh[4*kc+2] + hv.w * Uh[4*kc+3];
        }

        float zg = sigmoidf_(bf2f(cz) + az);
        float rg = sigmoidf_(bf2f(cr) + ar);
        float hh = tanh_fast(bf2f(ch) + rg * ah);
        if (AUG) zg *= cs;
        float hn = (1.f - zg) * h + zg * hh;
        h = (t < mylen) ? hn : h;

        asm volatile("" ::: "memory");  // all h_lds reads for step t precede the write
        h_lds[w][l] = h;
        asm volatile("" ::: "memory");  // write ordered before next step's reads (in-order DS pipe)
        if (!AUG) hor[(size_t)t * 64 + l] = f2bf(h);
    }
    if (AUG) hfinal[(size_t)b * 64 + l] = h;
}

// ---------------------------------------------------------------------------
// k_att: per-(b,t) attention MLP 256->64->16->1 (fp32 vector; MFMA next round).
// seq_h now bf16 (B,T,64).
// ---------------------------------------------------------------------------
__global__ __launch_bounds__(256) void k_att(
    const float* __restrict__ target, const unsigned short* __restrict__ seq_hb,
    const float* __restrict__ W1, const float* __restrict__ b1,
    const float* __restrict__ W2, const float* __restrict__ b2,
    const float* __restrict__ W3, const float* __restrict__ b3,
    const int* __restrict__ hist_len, float* __restrict__ logits)
{
    __shared__ float W1t[64][258];
    __shared__ float W2L[64][16];
    __shared__ float feats[4][8][256];
    __shared__ float a1s[4][8][64];

    const int tid = threadIdx.x;
    const int wv = tid >> 6, l = tid & 63;

    for (int i = tid; i < 256 * 64; i += 256) {
        int k = i >> 6, c = i & 63;
        W1t[c][k] = W1[i];
    }
    for (int i = tid; i < 64 * 16; i += 256) ((float*)W2L)[i] = W2[i];
    const float b1r = b1[l];
    const float b2r = b2[l & 15];
    const float w3r = W3[l & 15];
    const float b3r = b3[0];
    __syncthreads();

    const int ntile = (BB * TT) / 8;
    for (int tile = blockIdx.x * 4 + wv; tile < ntile; tile += gridDim.x * 4) {
        const int rowb = tile * 8;
        int bs[8], ts[8];
#pragma unroll
        for (int i = 0; i < 8; ++i) {
            int row = rowb + i;
            int b = row / TT, t = row - b * TT;
            bs[i] = b; ts[i] = t;
            float q = target[b * 64 + l];
            float h = bf2f(seq_hb[((size_t)b * TT + t) * 64 + l]);
            feats[wv][i][l] = q;
            feats[wv][i][64 + l] = h;
            feats[wv][i][128 + l] = q - h;
            feats[wv][i][192 + l] = q * h;
        }
        float acc[8] = {0.f, 0.f, 0.f, 0.f, 0.f, 0.f, 0.f, 0.f};
        for (int k = 0; k < 256; k += 2) {
            float2 wv2 = *(const float2*)&W1t[l][k];
#pragma unroll
            for (int i = 0; i < 8; ++i) {
                float2 f = *(const float2*)&feats[wv][i][k];
                acc[i] += f.x * wv2.x + f.y * wv2.y;
            }
        }
#pragma unroll
        for (int i = 0; i < 8; ++i) {
            float v = acc[i] + b1r;
            a1s[wv][i][l] = (v > 0.f) ? v : 0.25f * v;
        }
        const int j = l & 15, kq = l >> 4;
#pragma unroll
        for (int i = 0; i < 8; ++i) {
            float a2 = 0.f;
#pragma unroll
            for (int kk = 0; kk < 16; ++kk)
                a2 += a1s[wv][i][kq * 16 + kk] * W2L[kq * 16 + kk][j];
            a2 += __shfl_xor(a2, 16);
            a2 += __shfl_xor(a2, 32);
            a2 += b2r;
            a2 = (a2 > 0.f) ? a2 : 0.25f * a2;
            float part = a2 * w3r;
#pragma unroll
            for (int m = 1; m < 64; m <<= 1) part += __shfl_xor(part, m);
            if (l == 0) {
                float logit = 0.25f * part + b3r;
                int b = bs[i], t = ts[i];
                logit = (t < hist_len[b]) ? logit : -1e9f;
                logits[(size_t)b * TT + t] = logit;
            }
        }
    }
}

// ---------------------------------------------------------------------------
__global__ void k_softmax(float* __restrict__ scores) {
    int b = blockIdx.x, l = threadIdx.x;  // 64 threads
    float v[4];
#pragma unroll
    for (int j = 0; j < 4; ++j) {
        int t = l + 64 * j;
        v[j] = (t < TT) ? scores[(size_t)b * TT + t] : -1e30f;
    }
    float m = fmaxf(fmaxf(v[0], v[1]), fmaxf(v[2], v[3]));
#pragma unroll
    for (int s = 1; s < 64; s <<= 1) m = fmaxf(m, __shfl_xor(m, s));
    float e[4], sum = 0.f;
#pragma unroll
    for (int j = 0; j < 4; ++j) { e[j] = __expf(v[j] - m); sum += e[j]; }
#pragma unroll
    for (int s = 1; s < 64; s <<= 1) sum += __shfl_xor(sum, s);
    float inv = 1.f / sum;
#pragma unroll
    for (int j = 0; j < 4; ++j) {
        int t = l + 64 * j;
        if (t < TT) scores[(size_t)b * TT + t] = e[j] * inv;
    }
}

// ---------------------------------------------------------------------------
// FFN chain (tiny)
// ---------------------------------------------------------------------------
__global__ __launch_bounds__(256) void k_fc1(const float* __restrict__ fin,
                                             const float* __restrict__ tgt,
                                             const float* __restrict__ oth,
                                             const float* __restrict__ Wt,
                                             const float* __restrict__ bvec,
                                             float* __restrict__ fout) {
    __shared__ float z0[164];
    int b = blockIdx.x, tid = threadIdx.x;
    if (tid < 64) z0[tid] = fin[b * 64 + tid];
    else if (tid < 128) z0[tid] = tgt[b * 64 + tid - 64];
    else if (tid < 164) z0[tid] = oth[b * 36 + tid - 128];
    __syncthreads();
    float acc = bvec[tid];
#pragma unroll 4
    for (int k = 0; k < 164; ++k) acc += z0[k] * Wt[k * 256 + tid];
    fout[(size_t)b * 256 + tid] = acc;
}

template <int F>
__global__ __launch_bounds__(256) void k_stats(const float* __restrict__ x, float* __restrict__ stat) {
    int c = blockIdx.x, tid = threadIdx.x;
    float s = 0.f, sq = 0.f;
    for (int i = tid; i < BB; i += 256) {
        float v = x[(size_t)i * F + c];
        s += v; sq += v * v;
    }
#pragma unroll
    for (int m = 1; m < 64; m <<= 1) { s += __shfl_xor(s, m); sq += __shfl_xor(sq, m); }
    __shared__ float rs[4], rq[4];
    if ((tid & 63) == 0) { rs[tid >> 6] = s; rq[tid >> 6] = sq; }
    __syncthreads();
    if (tid == 0) {
        float S = rs[0] + rs[1] + rs[2] + rs[3];
        float Q = rq[0] + rq[1] + rq[2] + rq[3];
        float mean = S * (1.f / BB);
        float var = Q * (1.f / BB) - mean * mean;
        stat[c] = mean;
        stat[F + c] = var;
    }
}

__global__ __launch_bounds__(256) void k_fc2(const float* __restrict__ f1,
                                             const float* __restrict__ st1,
                                             const float* __restrict__ Wt,
                                             const float* __restrict__ bvec,
                                             float* __restrict__ f2) {
    __shared__ float z[256];
    int b = blockIdx.x, tid = threadIdx.x;
    float x = f1[(size_t)b * 256 + tid];
    z[tid] = dicef_(x, st1[tid], st1[256 + tid]);
    __syncthreads();
    if (tid < 128) {
        float acc = bvec[tid];
#pragma unroll 4
        for (int k = 0; k < 256; ++k) acc += z[k] * Wt[k * 128 + tid];
        f2[(size_t)b * 128 + tid] = acc;
    }
}

__global__ __launch_bounds__(128) void k_fc3(const float* __restrict__ f2,
                                             const float* __restrict__ st2,
                                             const float* __restrict__ Wt,
                                             const float* __restrict__ bvec,
                                             float* __restrict__ f3) {
    __shared__ float z[128];
    int b = blockIdx.x, tid = threadIdx.x;
    float x = f2[(size_t)b * 128 + tid];
    z[tid] = dicef_(x, st2[tid], st2[128 + tid]);
    __syncthreads();
    if (tid < 64) {
        float acc = bvec[tid];
#pragma unroll 4
        for (int k = 0; k < 128; ++k) acc += z[k] * Wt[k * 64 + tid];
        f3[(size_t)b * 64 + tid] = acc;
    }
}

__global__ void k_out(const float* __restrict__ f3, const float* __restrict__ st3,
                      const float* __restrict__ outW, const float* __restrict__ outb,
                      float* __restrict__ out) {
    int b = blockIdx.x, l = threadIdx.x;  // 64 threads
    float x = f3[(size_t)b * 64 + l];
    float z = dicef_(x, st3[l], st3[64 + l]);
    float p = z * outW[l];
#pragma unroll
    for (int m = 1; m < 64; m <<= 1) p += __shfl_xor(p, m);
    if (l == 0) out[b] = sigmoidf_(p + outb[0]);
}

// ---------------------------------------------------------------------------
extern "C" void kernel_launch(void* const* d_in, const int* in_sizes, int n_in,
                              void* d_out, int out_size, void* d_ws, size_t ws_size,
                              hipStream_t stream) {
    const float* dense      = (const float*)d_in[0];
    const int*   sparse     = (const int*)d_in[1];
    const int*   seq_idx    = (const int*)d_in[2];
    const int*   item_idx   = (const int*)d_in[3];
    const int*   hist_len   = (const int*)d_in[4];
    const float* item_table = (const float*)d_in[5];
    const float* other_tab  = (const float*)d_in[6];
    const float* gru_W = (const float*)d_in[7];
    const float* gru_U = (const float*)d_in[8];
    const float* gru_b = (const float*)d_in[9];
    const float* aug_W = (const float*)d_in[10];
    const float* aug_U = (const float*)d_in[11];
    const float* aug_b = (const float*)d_in[12];
    const float* att_W1 = (const float*)d_in[13];
    const float* att_b1 = (const float*)d_in[14];
    const float* att_W2 = (const float*)d_in[15];
    const float* att_b2 = (const float*)d_in[16];
    const float* att_W3 = (const float*)d_in[17];
    const float* att_b3 = (const float*)d_in[18];
    const float* ffn_W1 = (const float*)d_in[19];
    const float* ffn_b1 = (const float*)d_in[20];
    const float* ffn_W2 = (const float*)d_in[21];
    const float* ffn_b2 = (const float*)d_in[22];
    const float* ffn_W3 = (const float*)d_in[23];
    const float* ffn_b3 = (const float*)d_in[24];
    const float* out_W  = (const float*)d_in[25];
    const float* out_b  = (const float*)d_in[26];

    float* wsf = (float*)d_ws;
    // workspace layout (f32 slots); total ~27.0M f32 = 108 MB
    unsigned short* xwb   = (unsigned short*)(wsf);              // (B*T,192) bf16 = 19,660,800 f32 slots (reused for xw1 then xw2)
    unsigned short* seqhb = (unsigned short*)(wsf + 19660800);   // (B,T,64) bf16 = 6,553,600 f32 slots
    float* scores = wsf + 26214400;            // B*T    =    204,800
    float* target = wsf + 26419200;            // B*64   =     65,536
    float* other  = wsf + 26484736;            // B*36   =     36,864
    float* finals = wsf + 26521600;            // B*64   =     65,536
    float* f1     = wsf + 26587136;            // B*256  =    262,144
    float* f2     = wsf + 26849280;            // B*128  =    131,072
    float* f3     = wsf + 26980352;            // B*64   =     65,536
    float* st1    = wsf + 27045888;            // 512
    float* st2    = wsf + 27046400;            // 256
    float* st3    = wsf + 27046656;            // 128

    float* dout = (float*)d_out;
    const int Mtiles = (BB * TT) / 16;  // 12800

    k_prep<<<BB, 64, 0, stream>>>(dense, sparse, item_idx, item_table, other_tab, target, other);

    // xw1 = gather(item_table, seq_idx) @ gru_W + gru_b  (bf16 MFMA)
    k_xw<1><<<800, 256, 0, stream>>>(seq_idx, item_table, nullptr, gru_W, gru_b, xwb, Mtiles, 3200);

    // GRU1 recurrence -> seq_h bf16 (B,T,64)
    k_scan2<0><<<BB / 4, 256, 0, stream>>>(xwb, gru_U, hist_len, scores, seqhb, finals);

    k_att<<<256, 256, 0, stream>>>(target, seqhb, att_W1, att_b1, att_W2, att_b2,
                                   att_W3, att_b3, hist_len, scores);
    k_softmax<<<BB, 64, 0, stream>>>(scores);

    // xw2 = seq_h @ aug_W + aug_b  (bf16 MFMA, reuses xw buffer)
    k_xw<0><<<800, 256, 0, stream>>>(nullptr, nullptr, seqhb, aug_W, aug_b, xwb, Mtiles, 3200);

    // AUGRU recurrence -> finals f32 (B,64)
    k_scan2<1><<<BB / 4, 256, 0, stream>>>(xwb, aug_U, hist_len, scores, seqhb, finals);

    k_fc1<<<BB, 256, 0, stream>>>(finals, target, other, ffn_W1, ffn_b1, f1);
    k_stats<256><<<256, 256, 0, stream>>>(f1, st1);
    k_fc2<<<BB, 256, 0, stream>>>(f1, st1, ffn_W2, ffn_b2, f2);
    k_stats<128><<<128, 256, 0, stream>>>(f2, st2);
    k_fc3<<<BB, 128, 0, stream>>>(f2, st2, ffn_W3, ffn_b3, f3);
    k_stats<64><<<64, 256, 0, stream>>>(f3, st3);
    k_out<<<BB, 64, 0, stream>>>(f3, st3, out_W, out_b, dout);
}

// Round 3
// 479.683 us; speedup vs baseline: 2.1588x; 1.6079x over previous
//
#include <hip/hip_runtime.h>

#define BB 1024
#define TT 200

typedef __attribute__((ext_vector_type(8))) short short8;
typedef __attribute__((ext_vector_type(4))) float f32x4;

__device__ __forceinline__ float sigmoidf_(float x) { return __fdividef(1.0f, 1.0f + __expf(-x)); }
__device__ __forceinline__ float tanh_fast(float x) {
    x = fminf(15.f, fmaxf(-15.f, x));
    float e = __expf(-2.f * x);
    return __fdividef(1.f - e, 1.f + e);
}
__device__ __forceinline__ float dicef_(float x, float m, float v) {
    return x * sigmoidf_((x - m) * rsqrtf(v + 1e-9f));
}
__device__ __forceinline__ unsigned short f2bf(float f) {
    unsigned u = __float_as_uint(f);
    unsigned r = u + 0x7fffu + ((u >> 16) & 1u);
    return (unsigned short)(r >> 16);
}
__device__ __forceinline__ float bf2f(unsigned short h) {
    return __uint_as_float(((unsigned)h) << 16);
}
// pack 2 f32 -> 1 u32 of 2 bf16 (lo=src0, hi=src1), single HW instr
__device__ __forceinline__ unsigned cvt_pk_bf16(float lo, float hi) {
    unsigned r;
    asm("v_cvt_pk_bf16_f32 %0, %1, %2" : "=v"(r) : "v"(lo), "v"(hi));
    return r;
}
union U8 { short8 s8; unsigned u[4]; };

// ---------------------------------------------------------------------------
// k_prep: target_embed (B,64) f32 and other_info (B,36)
// ---------------------------------------------------------------------------
__global__ void k_prep(const float* __restrict__ dense, const int* __restrict__ sparse,
                       const int* __restrict__ item_idx, const float* __restrict__ table,
                       const float* __restrict__ other_tables,
                       float* __restrict__ target, float* __restrict__ other) {
    int b = blockIdx.x, l = threadIdx.x;  // 64 threads
    target[b * 64 + l] = table[(size_t)item_idx[b] * 64 + l];
    if (l < 4) other[b * 36 + l] = dense[b * 4 + l];
    else if (l < 20) other[b * 36 + l] = other_tables[(size_t)sparse[b * 2 + 0] * 16 + (l - 4)];
    else if (l < 36) other[b * 36 + l] = other_tables[1000 * 16 + (size_t)sparse[b * 2 + 1] * 16 + (l - 20)];
}

// ---------------------------------------------------------------------------
// k_xw: XW = X @ W + bias, bf16 MFMA 16x16x32 (unchanged from round 2)
// ---------------------------------------------------------------------------
template <int GATHER>
__global__ __launch_bounds__(256, 1) void k_xw(
    const int* __restrict__ idx, const float* __restrict__ tablef,
    const unsigned short* __restrict__ Abf,
    const float* __restrict__ W, const float* __restrict__ bias,
    unsigned short* __restrict__ out, int Mtiles, int tilestride)
{
    const int l = threadIdx.x & 63;
    const int wv = threadIdx.x >> 6;
    const int lg = l >> 4;
    const int li = l & 15;

    short8 bfr[12][2];
    float bn[12];
#pragma unroll
    for (int nt = 0; nt < 12; ++nt) {
        bn[nt] = bias[nt * 16 + li];
#pragma unroll
        for (int c = 0; c < 2; ++c) {
#pragma unroll
            for (int j = 0; j < 8; ++j) {
                int k = c * 32 + lg * 8 + j;
                bfr[nt][c][j] = (short)f2bf(W[k * 192 + nt * 16 + li]);
            }
        }
    }

    for (int tile = blockIdx.x * 4 + wv; tile < Mtiles; tile += tilestride) {
        short8 a[2];
        if (GATHER) {
            long row = (long)tile * 16 + li;
            long id = idx[row];
            const float* tp = tablef + id * 64 + lg * 8;
#pragma unroll
            for (int c = 0; c < 2; ++c) {
                f32x4 v0 = *(const f32x4*)(tp + c * 32);
                f32x4 v1 = *(const f32x4*)(tp + c * 32 + 4);
#pragma unroll
                for (int j = 0; j < 4; ++j) {
                    a[c][j] = (short)f2bf(v0[j]);
                    a[c][4 + j] = (short)f2bf(v1[j]);
                }
            }
        } else {
            long row = (long)tile * 16 + li;
#pragma unroll
            for (int c = 0; c < 2; ++c)
                a[c] = *(const short8*)(Abf + row * 64 + c * 32 + lg * 8);
        }

        f32x4 acc[12];
#pragma unroll
        for (int nt = 0; nt < 12; ++nt) acc[nt] = (f32x4){0.f, 0.f, 0.f, 0.f};
#pragma unroll
        for (int c = 0; c < 2; ++c)
#pragma unroll
            for (int nt = 0; nt < 12; ++nt)
                acc[nt] = __builtin_amdgcn_mfma_f32_16x16x32_bf16(a[c], bfr[nt][c], acc[nt], 0, 0, 0);

#pragma unroll
        for (int nt = 0; nt < 12; ++nt)
#pragma unroll
            for (int j = 0; j < 4; ++j) {
                long row = (long)tile * 16 + lg * 4 + j;
                out[row * 192 + nt * 16 + li] = f2bf(acc[nt][j] + bn[nt]);
            }
    }
}

// ---------------------------------------------------------------------------
// k_scan2: recurrent h@U only (unchanged from round 2)
// ---------------------------------------------------------------------------
template <int AUG>
__global__ __launch_bounds__(256, 1) void k_scan2(
    const unsigned short* __restrict__ xw,
    const float* __restrict__ U,
    const int* __restrict__ hist_len,
    const float* __restrict__ scores,
    unsigned short* __restrict__ hout,
    float* __restrict__ hfinal)
{
    __shared__ float h_lds[4][64];
    const int w = threadIdx.x >> 6, l = threadIdx.x & 63;
    const int b = blockIdx.x * 4 + w;

    float Uz[64], Ur[64], Uh[64];
#pragma unroll
    for (int k = 0; k < 64; ++k) {
        Uz[k] = U[k * 192 + l];
        Ur[k] = U[k * 192 + 64 + l];
        Uh[k] = U[k * 192 + 128 + l];
    }
    const int mylen = hist_len[b];
    const unsigned short* xwr = xw + (size_t)b * TT * 192;
    const float* scr = scores + (size_t)b * TT;
    unsigned short* hor = hout + (size_t)b * TT * 64;

    float h = 0.f;
    h_lds[w][l] = 0.f;
    asm volatile("" ::: "memory");

    unsigned short nz = xwr[l], nr = xwr[64 + l], nh = xwr[128 + l];
    float ns = AUG ? scr[0] : 0.f;

    for (int t = 0; t < TT; ++t) {
        const unsigned short cz = nz, cr = nr, ch = nh;
        const float cs = ns;
        if (t + 1 < TT) {
            const unsigned short* p = xwr + (size_t)(t + 1) * 192;
            nz = p[l]; nr = p[64 + l]; nh = p[128 + l];
            if (AUG) ns = scr[t + 1];
        }

        float az = 0.f, ar = 0.f, ah = 0.f;
        const float4* h4 = (const float4*)(&h_lds[w][0]);
#pragma unroll
        for (int kc = 0; kc < 16; ++kc) {
            float4 hv = h4[kc];
            az += hv.x * Uz[4*kc] + hv.y * Uz[4*kc+1] + hv.z * Uz[4*kc+2] + hv.w * Uz[4*kc+3];
            ar += hv.x * Ur[4*kc] + hv.y * Ur[4*kc+1] + hv.z * Ur[4*kc+2] + hv.w * Ur[4*kc+3];
            ah += hv.x * Uh[4*kc] + hv.y * Uh[4*kc+1] + hv.z * Uh[4*kc+2] + hv.w * Uh[4*kc+3];
        }

        float zg = sigmoidf_(bf2f(cz) + az);
        float rg = sigmoidf_(bf2f(cr) + ar);
        float hh = tanh_fast(bf2f(ch) + rg * ah);
        if (AUG) zg *= cs;
        float hn = (1.f - zg) * h + zg * hh;
        h = (t < mylen) ? hn : h;

        asm volatile("" ::: "memory");
        h_lds[w][l] = h;
        asm volatile("" ::: "memory");
        if (!AUG) hor[(size_t)t * 64 + l] = f2bf(h);
    }
    if (AUG) hfinal[(size_t)b * 64 + l] = h;
}

// ---------------------------------------------------------------------------
// k_att: bf16 MFMA attention + fused softmax. One block (4 waves) per batch
// row b. feats=[q,h,q-h,q*h] built as A-fragments in registers (never
// materialized). W1 staged to LDS in fragment layout once, then
// register-resident (32 x short8). Layers: 256->64 (32 MFMA), LDS transpose,
// 64->16 (2 MFMA), 16->1 (shuffle reduce). Block softmax -> scores.
// ---------------------------------------------------------------------------
__global__ __launch_bounds__(256, 2) void k_att(
    const float* __restrict__ target, const unsigned short* __restrict__ seq_hb,
    const float* __restrict__ W1, const float* __restrict__ b1,
    const float* __restrict__ W2, const float* __restrict__ b2,
    const float* __restrict__ W3, const float* __restrict__ b3,
    const int* __restrict__ hist_len, float* __restrict__ scores)
{
    __shared__ unsigned short W1f[8 * 4 * 64 * 8];  // frag layout, 32 KB
    __shared__ float a1s[4][16][68];                // per-wave transpose slab
    __shared__ float logit_lds[208];
    __shared__ float red[8];

    const int tid = threadIdx.x;
    const int wv = tid >> 6, l = tid & 63;
    const int lg = l >> 4, li = l & 15;
    const int b = blockIdx.x;
    const int len = hist_len[b];

    // stage W1 (256x64 f32) -> LDS bf16 fragments: idx ((c*4+nt)*64 + l)*8 + j
    for (int i = tid; i < 8 * 4 * 64 * 8; i += 256) {
        int j = i & 7, ll = (i >> 3) & 63, nt = (i >> 9) & 3, c = i >> 11;
        int k = c * 32 + (ll >> 4) * 8 + j;
        int col = nt * 16 + (ll & 15);
        W1f[i] = f2bf(W1[k * 64 + col]);
    }
    __syncthreads();

    // register-resident fragments
    short8 w1r[8][4];
    const short8* wf = (const short8*)W1f;
#pragma unroll
    for (int c = 0; c < 8; ++c)
#pragma unroll
        for (int nt = 0; nt < 4; ++nt)
            w1r[c][nt] = wf[(c * 4 + nt) * 64 + l];

    short8 w2r[2];
#pragma unroll
    for (int c = 0; c < 2; ++c) {
        U8 t8;
#pragma unroll
        for (int m = 0; m < 4; ++m) {
            int k0 = c * 32 + lg * 8 + 2 * m;
            t8.u[m] = cvt_pk_bf16(W2[k0 * 16 + li], W2[(k0 + 1) * 16 + li]);
        }
        w2r[c] = t8.s8;
    }

    float b1v[4];
#pragma unroll
    for (int nt = 0; nt < 4; ++nt) b1v[nt] = b1[nt * 16 + li];
    const float b2v = b2[li];
    const float w3v = W3[li];
    const float b3r = b3[0];

    // q fragments (constant per block)
    const float* qp = target + (size_t)b * 64;
    float qf_lo[8], qf_hi[8];
#pragma unroll
    for (int j = 0; j < 8; ++j) { qf_lo[j] = qp[lg * 8 + j]; qf_hi[j] = qp[32 + lg * 8 + j]; }
    U8 q8l, q8h;
#pragma unroll
    for (int m = 0; m < 4; ++m) {
        q8l.u[m] = cvt_pk_bf16(qf_lo[2 * m], qf_lo[2 * m + 1]);
        q8h.u[m] = cvt_pk_bf16(qf_hi[2 * m], qf_hi[2 * m + 1]);
    }

    // 13 M-tiles of 16 t-rows; wave w takes tiles w, w+4, w+8, (w+12)
    for (int mt = wv; mt < 13; mt += 4) {
        const int t = mt * 16 + li;
        const int tld = (t < TT) ? t : TT - 1;
        const unsigned short* hp = seq_hb + ((size_t)b * TT + tld) * 64 + lg * 8;
        short8 h8l = *(const short8*)hp;
        short8 h8h = *(const short8*)(hp + 32);

        // build d = q-h, m = q*h fragments in f32, pack to bf16
        float hf;
        U8 d8l, d8h, m8l, m8h;
#pragma unroll
        for (int m = 0; m < 4; ++m) {
            float h0, h1, d0, d1, p0, p1;
            h0 = bf2f((unsigned short)h8l[2 * m]); h1 = bf2f((unsigned short)h8l[2 * m + 1]);
            d0 = qf_lo[2 * m] - h0; d1 = qf_lo[2 * m + 1] - h1;
            p0 = qf_lo[2 * m] * h0; p1 = qf_lo[2 * m + 1] * h1;
            d8l.u[m] = cvt_pk_bf16(d0, d1);
            m8l.u[m] = cvt_pk_bf16(p0, p1);
            h0 = bf2f((unsigned short)h8h[2 * m]); h1 = bf2f((unsigned short)h8h[2 * m + 1]);
            d0 = qf_hi[2 * m] - h0; d1 = qf_hi[2 * m + 1] - h1;
            p0 = qf_hi[2 * m] * h0; p1 = qf_hi[2 * m + 1] * h1;
            d8h.u[m] = cvt_pk_bf16(d0, d1);
            m8h.u[m] = cvt_pk_bf16(p0, p1);
        }
        (void)hf;

        // layer 1: 8 k-chunks x 4 n-tiles
        f32x4 acc[4];
#pragma unroll
        for (int nt = 0; nt < 4; ++nt) acc[nt] = (f32x4){0.f, 0.f, 0.f, 0.f};
#pragma unroll
        for (int nt = 0; nt < 4; ++nt) {
            acc[nt] = __builtin_amdgcn_mfma_f32_16x16x32_bf16(q8l.s8, w1r[0][nt], acc[nt], 0, 0, 0);
            acc[nt] = __builtin_amdgcn_mfma_f32_16x16x32_bf16(q8h.s8, w1r[1][nt], acc[nt], 0, 0, 0);
            acc[nt] = __builtin_amdgcn_mfma_f32_16x16x32_bf16(h8l,    w1r[2][nt], acc[nt], 0, 0, 0);
            acc[nt] = __builtin_amdgcn_mfma_f32_16x16x32_bf16(h8h,    w1r[3][nt], acc[nt], 0, 0, 0);
            acc[nt] = __builtin_amdgcn_mfma_f32_16x16x32_bf16(d8l.s8, w1r[4][nt], acc[nt], 0, 0, 0);
            acc[nt] = __builtin_amdgcn_mfma_f32_16x16x32_bf16(d8h.s8, w1r[5][nt], acc[nt], 0, 0, 0);
            acc[nt] = __builtin_amdgcn_mfma_f32_16x16x32_bf16(m8l.s8, w1r[6][nt], acc[nt], 0, 0, 0);
            acc[nt] = __builtin_amdgcn_mfma_f32_16x16x32_bf16(m8h.s8, w1r[7][nt], acc[nt], 0, 0, 0);
        }

        // bias + prelu -> wave-private LDS transpose slab (C layout: row=lg*4+jj, col=nt*16+li)
#pragma unroll
        for (int nt = 0; nt < 4; ++nt)
#pragma unroll
            for (int jj = 0; jj < 4; ++jj) {
                float v = acc[nt][jj] + b1v[nt];
                a1s[wv][lg * 4 + jj][nt * 16 + li] = (v > 0.f) ? v : 0.25f * v;
            }

        // layer 2: A-frag = a1[row=li][k=c2*32+lg*8+j] from slab, 2 MFMAs
        const float* arow = &a1s[wv][li][0];
        f32x4 acc2 = (f32x4){0.f, 0.f, 0.f, 0.f};
#pragma unroll
        for (int c2 = 0; c2 < 2; ++c2) {
            f32x4 v0 = *(const f32x4*)(arow + c2 * 32 + lg * 8);
            f32x4 v1 = *(const f32x4*)(arow + c2 * 32 + lg * 8 + 4);
            U8 a2f;
            a2f.u[0] = cvt_pk_bf16(v0[0], v0[1]);
            a2f.u[1] = cvt_pk_bf16(v0[2], v0[3]);
            a2f.u[2] = cvt_pk_bf16(v1[0], v1[1]);
            a2f.u[3] = cvt_pk_bf16(v1[2], v1[3]);
            acc2 = __builtin_amdgcn_mfma_f32_16x16x32_bf16(a2f.s8, w2r[c2], acc2, 0, 0, 0);
        }

        // layer 3: prelu, *W3, reduce over 16 cols (lanes li), write logits
#pragma unroll
        for (int jj = 0; jj < 4; ++jj) {
            float a2 = acc2[jj] + b2v;
            a2 = (a2 > 0.f) ? a2 : 0.25f * a2;
            float part = a2 * w3v;
            part += __shfl_xor(part, 1);
            part += __shfl_xor(part, 2);
            part += __shfl_xor(part, 4);
            part += __shfl_xor(part, 8);
            int tt = mt * 16 + lg * 4 + jj;
            if (li == 0 && tt < TT)
                logit_lds[tt] = (tt < len) ? (part + b3r) : -1e9f;
        }
    }
    __syncthreads();

    // fused masked softmax over the block's 200 logits
    float v = (tid < TT) ? logit_lds[tid] : -1e30f;
    float m = v;
#pragma unroll
    for (int s = 1; s < 64; s <<= 1) m = fmaxf(m, __shfl_xor(m, s));
    if (l == 0) red[wv] = m;
    __syncthreads();
    m = fmaxf(fmaxf(red[0], red[1]), fmaxf(red[2], red[3]));
    float e = (tid < TT) ? __expf(v - m) : 0.f;
    float sum = e;
#pragma unroll
    for (int s = 1; s < 64; s <<= 1) sum += __shfl_xor(sum, s);
    if (l == 0) red[4 + wv] = sum;
    __syncthreads();
    float inv = __fdividef(1.f, red[4] + red[5] + red[6] + red[7]);
    if (tid < TT) scores[(size_t)b * TT + tid] = e * inv;
}

// ---------------------------------------------------------------------------
// FFN chain (tiny, unchanged)
// ---------------------------------------------------------------------------
__global__ __launch_bounds__(256) void k_fc1(const float* __restrict__ fin,
                                             const float* __restrict__ tgt,
                                             const float* __restrict__ oth,
                                             const float* __restrict__ Wt,
                                             const float* __restrict__ bvec,
                                             float* __restrict__ fout) {
    __shared__ float z0[164];
    int b = blockIdx.x, tid = threadIdx.x;
    if (tid < 64) z0[tid] = fin[b * 64 + tid];
    else if (tid < 128) z0[tid] = tgt[b * 64 + tid - 64];
    else if (tid < 164) z0[tid] = oth[b * 36 + tid - 128];
    __syncthreads();
    float acc = bvec[tid];
#pragma unroll 4
    for (int k = 0; k < 164; ++k) acc += z0[k] * Wt[k * 256 + tid];
    fout[(size_t)b * 256 + tid] = acc;
}

template <int F>
__global__ __launch_bounds__(256) void k_stats(const float* __restrict__ x, float* __restrict__ stat) {
    int c = blockIdx.x, tid = threadIdx.x;
    float s = 0.f, sq = 0.f;
    for (int i = tid; i < BB; i += 256) {
        float v = x[(size_t)i * F + c];
        s += v; sq += v * v;
    }
#pragma unroll
    for (int m = 1; m < 64; m <<= 1) { s += __shfl_xor(s, m); sq += __shfl_xor(sq, m); }
    __shared__ float rs[4], rq[4];
    if ((tid & 63) == 0) { rs[tid >> 6] = s; rq[tid >> 6] = sq; }
    __syncthreads();
    if (tid == 0) {
        float S = rs[0] + rs[1] + rs[2] + rs[3];
        float Q = rq[0] + rq[1] + rq[2] + rq[3];
        float mean = S * (1.f / BB);
        float var = Q * (1.f / BB) - mean * mean;
        stat[c] = mean;
        stat[F + c] = var;
    }
}

__global__ __launch_bounds__(256) void k_fc2(const float* __restrict__ f1,
                                             const float* __restrict__ st1,
                                             const float* __restrict__ Wt,
                                             const float* __restrict__ bvec,
                                             float* __restrict__ f2) {
    __shared__ float z[256];
    int b = blockIdx.x, tid = threadIdx.x;
    float x = f1[(size_t)b * 256 + tid];
    z[tid] = dicef_(x, st1[tid], st1[256 + tid]);
    __syncthreads();
    if (tid < 128) {
        float acc = bvec[tid];
#pragma unroll 4
        for (int k = 0; k < 256; ++k) acc += z[k] * Wt[k * 128 + tid];
        f2[(size_t)b * 128 + tid] = acc;
    }
}

__global__ __launch_bounds__(128) void k_fc3(const float* __restrict__ f2,
                                             const float* __restrict__ st2,
                                             const float* __restrict__ Wt,
                                             const float* __restrict__ bvec,
                                             float* __restrict__ f3) {
    __shared__ float z[128];
    int b = blockIdx.x, tid = threadIdx.x;
    float x = f2[(size_t)b * 128 + tid];
    z[tid] = dicef_(x, st2[tid], st2[128 + tid]);
    __syncthreads();
    if (tid < 64) {
        float acc = bvec[tid];
#pragma unroll 4
        for (int k = 0; k < 128; ++k) acc += z[k] * Wt[k * 64 + tid];
        f3[(size_t)b * 64 + tid] = acc;
    }
}

__global__ void k_out(const float* __restrict__ f3, const float* __restrict__ st3,
                      const float* __restrict__ outW, const float* __restrict__ outb,
                      float* __restrict__ out) {
    int b = blockIdx.x, l = threadIdx.x;  // 64 threads
    float x = f3[(size_t)b * 64 + l];
    float z = dicef_(x, st3[l], st3[64 + l]);
    float p = z * outW[l];
#pragma unroll
    for (int m = 1; m < 64; m <<= 1) p += __shfl_xor(p, m);
    if (l == 0) out[b] = sigmoidf_(p + outb[0]);
}

// ---------------------------------------------------------------------------
extern "C" void kernel_launch(void* const* d_in, const int* in_sizes, int n_in,
                              void* d_out, int out_size, void* d_ws, size_t ws_size,
                              hipStream_t stream) {
    const float* dense      = (const float*)d_in[0];
    const int*   sparse     = (const int*)d_in[1];
    const int*   seq_idx    = (const int*)d_in[2];
    const int*   item_idx   = (const int*)d_in[3];
    const int*   hist_len   = (const int*)d_in[4];
    const float* item_table = (const float*)d_in[5];
    const float* other_tab  = (const float*)d_in[6];
    const float* gru_W = (const float*)d_in[7];
    const float* gru_U = (const float*)d_in[8];
    const float* gru_b = (const float*)d_in[9];
    const float* aug_W = (const float*)d_in[10];
    const float* aug_U = (const float*)d_in[11];
    const float* aug_b = (const float*)d_in[12];
    const float* att_W1 = (const float*)d_in[13];
    const float* att_b1 = (const float*)d_in[14];
    const float* att_W2 = (const float*)d_in[15];
    const float* att_b2 = (const float*)d_in[16];
    const float* att_W3 = (const float*)d_in[17];
    const float* att_b3 = (const float*)d_in[18];
    const float* ffn_W1 = (const float*)d_in[19];
    const float* ffn_b1 = (const float*)d_in[20];
    const float* ffn_W2 = (const float*)d_in[21];
    const float* ffn_b2 = (const float*)d_in[22];
    const float* ffn_W3 = (const float*)d_in[23];
    const float* ffn_b3 = (const float*)d_in[24];
    const float* out_W  = (const float*)d_in[25];
    const float* out_b  = (const float*)d_in[26];

    float* wsf = (float*)d_ws;
    unsigned short* xwb   = (unsigned short*)(wsf);              // (B*T,192) bf16
    unsigned short* seqhb = (unsigned short*)(wsf + 19660800);   // (B,T,64) bf16
    float* scores = wsf + 26214400;            // B*T
    float* target = wsf + 26419200;            // B*64
    float* other  = wsf + 26484736;            // B*36
    float* finals = wsf + 26521600;            // B*64
    float* f1     = wsf + 26587136;            // B*256
    float* f2     = wsf + 26849280;            // B*128
    float* f3     = wsf + 26980352;            // B*64
    float* st1    = wsf + 27045888;            // 512
    float* st2    = wsf + 27046400;            // 256
    float* st3    = wsf + 27046656;            // 128

    float* dout = (float*)d_out;
    const int Mtiles = (BB * TT) / 16;  // 12800

    k_prep<<<BB, 64, 0, stream>>>(dense, sparse, item_idx, item_table, other_tab, target, other);

    // xw1 = gather(item_table, seq_idx) @ gru_W + gru_b  (bf16 MFMA)
    k_xw<1><<<800, 256, 0, stream>>>(seq_idx, item_table, nullptr, gru_W, gru_b, xwb, Mtiles, 3200);

    // GRU1 recurrence -> seq_h bf16 (B,T,64)
    k_scan2<0><<<BB / 4, 256, 0, stream>>>(xwb, gru_U, hist_len, scores, seqhb, finals);

    // attention MLP (MFMA) + fused softmax -> scores
    k_att<<<BB, 256, 0, stream>>>(target, seqhb, att_W1, att_b1, att_W2, att_b2,
                                  att_W3, att_b3, hist_len, scores);

    // xw2 = seq_h @ aug_W + aug_b  (bf16 MFMA, reuses xw buffer)
    k_xw<0><<<800, 256, 0, stream>>>(nullptr, nullptr, seqhb, aug_W, aug_b, xwb, Mtiles, 3200);

    // AUGRU recurrence -> finals f32 (B,64)
    k_scan2<1><<<BB / 4, 256, 0, stream>>>(xwb, aug_U, hist_len, scores, seqhb, finals);

    k_fc1<<<BB, 256, 0, stream>>>(finals, target, other, ffn_W1, ffn_b1, f1);
    k_stats<256><<<256, 256, 0, stream>>>(f1, st1);
    k_fc2<<<BB, 256, 0, stream>>>(f1, st1, ffn_W2, ffn_b2, f2);
    k_stats<128><<<128, 256, 0, stream>>>(f2, st2);
    k_fc3<<<BB, 128, 0, stream>>>(f2, st2, ffn_W3, ffn_b3, f3);
    k_stats<64><<<64, 256, 0, stream>>>(f3, st3);
    k_out<<<BB, 64, 0, stream>>>(f3, st3, out_W, out_b, dout);
}

// Round 4
// 431.022 us; speedup vs baseline: 2.4025x; 1.1129x over previous
//
#include <hip/hip_runtime.h>

#define BB 1024
#define TT 200

typedef __attribute__((ext_vector_type(8))) short short8;
typedef __attribute__((ext_vector_type(4))) float f32x4;

__device__ __forceinline__ float sigmoidf_(float x) { return __fdividef(1.0f, 1.0f + __expf(-x)); }
__device__ __forceinline__ float tanh_fast(float x) {
    x = fminf(15.f, fmaxf(-15.f, x));
    float e = __expf(-2.f * x);
    return __fdividef(1.f - e, 1.f + e);
}
__device__ __forceinline__ float dicef_(float x, float m, float v) {
    return x * sigmoidf_((x - m) * rsqrtf(v + 1e-9f));
}
__device__ __forceinline__ unsigned short f2bf(float f) {
    unsigned u = __float_as_uint(f);
    unsigned r = u + 0x7fffu + ((u >> 16) & 1u);
    return (unsigned short)(r >> 16);
}
__device__ __forceinline__ float bf2f(unsigned short h) {
    return __uint_as_float(((unsigned)h) << 16);
}
// pack 2 f32 -> 1 u32 of 2 bf16 (lo=src0, hi=src1), single HW instr
__device__ __forceinline__ unsigned cvt_pk_bf16(float lo, float hi) {
    unsigned r;
    asm("v_cvt_pk_bf16_f32 %0, %1, %2" : "=v"(r) : "v"(lo), "v"(hi));
    return r;
}
union U8 { short8 s8; unsigned u[4]; };

// ---------------------------------------------------------------------------
// k_prep: target_embed (B,64) f32 and other_info (B,36)
// ---------------------------------------------------------------------------
__global__ void k_prep(const float* __restrict__ dense, const int* __restrict__ sparse,
                       const int* __restrict__ item_idx, const float* __restrict__ table,
                       const float* __restrict__ other_tables,
                       float* __restrict__ target, float* __restrict__ other) {
    int b = blockIdx.x, l = threadIdx.x;  // 64 threads
    target[b * 64 + l] = table[(size_t)item_idx[b] * 64 + l];
    if (l < 4) other[b * 36 + l] = dense[b * 4 + l];
    else if (l < 20) other[b * 36 + l] = other_tables[(size_t)sparse[b * 2 + 0] * 16 + (l - 4)];
    else if (l < 36) other[b * 36 + l] = other_tables[1000 * 16 + (size_t)sparse[b * 2 + 1] * 16 + (l - 20)];
}

// ---------------------------------------------------------------------------
// k_xw: XW = X @ W + bias, bf16 MFMA 16x16x32 (unchanged)
// ---------------------------------------------------------------------------
template <int GATHER>
__global__ __launch_bounds__(256, 1) void k_xw(
    const int* __restrict__ idx, const float* __restrict__ tablef,
    const unsigned short* __restrict__ Abf,
    const float* __restrict__ W, const float* __restrict__ bias,
    unsigned short* __restrict__ out, int Mtiles, int tilestride)
{
    const int l = threadIdx.x & 63;
    const int wv = threadIdx.x >> 6;
    const int lg = l >> 4;
    const int li = l & 15;

    short8 bfr[12][2];
    float bn[12];
#pragma unroll
    for (int nt = 0; nt < 12; ++nt) {
        bn[nt] = bias[nt * 16 + li];
#pragma unroll
        for (int c = 0; c < 2; ++c) {
#pragma unroll
            for (int j = 0; j < 8; ++j) {
                int k = c * 32 + lg * 8 + j;
                bfr[nt][c][j] = (short)f2bf(W[k * 192 + nt * 16 + li]);
            }
        }
    }

    for (int tile = blockIdx.x * 4 + wv; tile < Mtiles; tile += tilestride) {
        short8 a[2];
        if (GATHER) {
            long row = (long)tile * 16 + li;
            long id = idx[row];
            const float* tp = tablef + id * 64 + lg * 8;
#pragma unroll
            for (int c = 0; c < 2; ++c) {
                f32x4 v0 = *(const f32x4*)(tp + c * 32);
                f32x4 v1 = *(const f32x4*)(tp + c * 32 + 4);
#pragma unroll
                for (int j = 0; j < 4; ++j) {
                    a[c][j] = (short)f2bf(v0[j]);
                    a[c][4 + j] = (short)f2bf(v1[j]);
                }
            }
        } else {
            long row = (long)tile * 16 + li;
#pragma unroll
            for (int c = 0; c < 2; ++c)
                a[c] = *(const short8*)(Abf + row * 64 + c * 32 + lg * 8);
        }

        f32x4 acc[12];
#pragma unroll
        for (int nt = 0; nt < 12; ++nt) acc[nt] = (f32x4){0.f, 0.f, 0.f, 0.f};
#pragma unroll
        for (int c = 0; c < 2; ++c)
#pragma unroll
            for (int nt = 0; nt < 12; ++nt)
                acc[nt] = __builtin_amdgcn_mfma_f32_16x16x32_bf16(a[c], bfr[nt][c], acc[nt], 0, 0, 0);

#pragma unroll
        for (int nt = 0; nt < 12; ++nt)
#pragma unroll
            for (int j = 0; j < 4; ++j) {
                long row = (long)tile * 16 + lg * 4 + j;
                out[row * 192 + nt * 16 + li] = f2bf(acc[nt][j] + bn[nt]);
            }
    }
}

// ---------------------------------------------------------------------------
// k_scan3: recurrent h@U, 4-way k-split. One block (4 waves) per batch row.
// Wave w owns k in [16w,16w+16) -> only 48 U-floats/thread (no spill).
// Per step: partial dots -> part[] -> barrier -> ROTATING gate wave (t&3)
// reduces + computes gates + writes h -> barrier. Gate wave for t+1
// prefetches its xw row during step t (hidden under dots/gates).
// Grid = 1024 blocks -> 4 waves/SIMD occupancy.
// ---------------------------------------------------------------------------
template <int AUG>
__global__ __launch_bounds__(256, 4) void k_scan3(
    const unsigned short* __restrict__ xw,
    const float* __restrict__ U,
    const int* __restrict__ hist_len,
    const float* __restrict__ scores,
    unsigned short* __restrict__ hout,
    float* __restrict__ hfinal)
{
    __shared__ float h_lds[64];
    __shared__ float part[3][4][64];   // [gate][kchunk][col]

    const int tid = threadIdx.x;
    const int w = tid >> 6, l = tid & 63;
    const int b = blockIdx.x;

    // register-resident U slice: k in [16w, 16w+16)
    float Uz[16], Ur[16], Uh[16];
#pragma unroll
    for (int kk = 0; kk < 16; ++kk) {
        int k = w * 16 + kk;
        Uz[kk] = U[k * 192 + l];
        Ur[kk] = U[k * 192 + 64 + l];
        Uh[kk] = U[k * 192 + 128 + l];
    }
    const unsigned short* xwr = xw + (size_t)b * TT * 192;
    const float* scr = scores + (size_t)b * TT;
    unsigned short* hor = hout + (size_t)b * TT * 64;
    const int mylen = hist_len[b];

    // xw prefetch registers (valid only in the wave that gates at that step)
    unsigned short nz = 0, nr_ = 0, nh = 0;
    float ns = 0.f;
    if (w == 0) {                       // gate wave for t=0
        nz = xwr[l]; nr_ = xwr[64 + l]; nh = xwr[128 + l];
        if (AUG) ns = scr[0];
        h_lds[l] = 0.f;
    }
    __syncthreads();

    for (int t = 0; t < TT; ++t) {
        // prefetch for step t+1, done by that step's gate wave (off crit path)
        if (t + 1 < TT && ((t + 1) & 3) == w) {
            const unsigned short* p = xwr + (size_t)(t + 1) * 192;
            nz = p[l]; nr_ = p[64 + l]; nh = p[128 + l];
            if (AUG) ns = scr[t + 1];
        }

        // partial dots over this wave's k-chunk (uniform-address broadcast reads)
        float az = 0.f, ar = 0.f, ah = 0.f;
        const float4* h4 = (const float4*)(&h_lds[w * 16]);
#pragma unroll
        for (int kc = 0; kc < 4; ++kc) {
            float4 hv = h4[kc];
            az += hv.x * Uz[4*kc] + hv.y * Uz[4*kc+1] + hv.z * Uz[4*kc+2] + hv.w * Uz[4*kc+3];
            ar += hv.x * Ur[4*kc] + hv.y * Ur[4*kc+1] + hv.z * Ur[4*kc+2] + hv.w * Ur[4*kc+3];
            ah += hv.x * Uh[4*kc] + hv.y * Uh[4*kc+1] + hv.z * Uh[4*kc+2] + hv.w * Uh[4*kc+3];
        }
        part[0][w][l] = az;
        part[1][w][l] = ar;
        part[2][w][l] = ah;
        __syncthreads();  // bar1: partials visible; h_lds reads of step t done

        if ((t & 3) == w) {
            float azf = part[0][0][l] + part[0][1][l] + part[0][2][l] + part[0][3][l];
            float arf = part[1][0][l] + part[1][1][l] + part[1][2][l] + part[1][3][l];
            float ahf = part[2][0][l] + part[2][1][l] + part[2][2][l] + part[2][3][l];
            float hprev = h_lds[l];

            float zg = sigmoidf_(bf2f(nz) + azf);
            float rg = sigmoidf_(bf2f(nr_) + arf);
            float hh = tanh_fast(bf2f(nh) + rg * ahf);
            if (AUG) zg *= ns;
            float hn = (1.f - zg) * hprev + zg * hh;
            float hval = (t < mylen) ? hn : hprev;
            h_lds[l] = hval;
            if (!AUG) hor[(size_t)t * 64 + l] = f2bf(hval);
        }
        __syncthreads();  // bar2: new h visible before next step's dots
    }
    if (AUG && w == 0) hfinal[(size_t)b * 64 + l] = h_lds[l];
}

// ---------------------------------------------------------------------------
// k_att: bf16 MFMA attention + fused softmax (unchanged from round 3)
// ---------------------------------------------------------------------------
__global__ __launch_bounds__(256, 2) void k_att(
    const float* __restrict__ target, const unsigned short* __restrict__ seq_hb,
    const float* __restrict__ W1, const float* __restrict__ b1,
    const float* __restrict__ W2, const float* __restrict__ b2,
    const float* __restrict__ W3, const float* __restrict__ b3,
    const int* __restrict__ hist_len, float* __restrict__ scores)
{
    __shared__ unsigned short W1f[8 * 4 * 64 * 8];  // frag layout, 32 KB
    __shared__ float a1s[4][16][68];                // per-wave transpose slab
    __shared__ float logit_lds[208];
    __shared__ float red[8];

    const int tid = threadIdx.x;
    const int wv = tid >> 6, l = tid & 63;
    const int lg = l >> 4, li = l & 15;
    const int b = blockIdx.x;
    const int len = hist_len[b];

    for (int i = tid; i < 8 * 4 * 64 * 8; i += 256) {
        int j = i & 7, ll = (i >> 3) & 63, nt = (i >> 9) & 3, c = i >> 11;
        int k = c * 32 + (ll >> 4) * 8 + j;
        int col = nt * 16 + (ll & 15);
        W1f[i] = f2bf(W1[k * 64 + col]);
    }
    __syncthreads();

    short8 w1r[8][4];
    const short8* wf = (const short8*)W1f;
#pragma unroll
    for (int c = 0; c < 8; ++c)
#pragma unroll
        for (int nt = 0; nt < 4; ++nt)
            w1r[c][nt] = wf[(c * 4 + nt) * 64 + l];

    short8 w2r[2];
#pragma unroll
    for (int c = 0; c < 2; ++c) {
        U8 t8;
#pragma unroll
        for (int m = 0; m < 4; ++m) {
            int k0 = c * 32 + lg * 8 + 2 * m;
            t8.u[m] = cvt_pk_bf16(W2[k0 * 16 + li], W2[(k0 + 1) * 16 + li]);
        }
        w2r[c] = t8.s8;
    }

    float b1v[4];
#pragma unroll
    for (int nt = 0; nt < 4; ++nt) b1v[nt] = b1[nt * 16 + li];
    const float b2v = b2[li];
    const float w3v = W3[li];
    const float b3r = b3[0];

    const float* qp = target + (size_t)b * 64;
    float qf_lo[8], qf_hi[8];
#pragma unroll
    for (int j = 0; j < 8; ++j) { qf_lo[j] = qp[lg * 8 + j]; qf_hi[j] = qp[32 + lg * 8 + j]; }
    U8 q8l, q8h;
#pragma unroll
    for (int m = 0; m < 4; ++m) {
        q8l.u[m] = cvt_pk_bf16(qf_lo[2 * m], qf_lo[2 * m + 1]);
        q8h.u[m] = cvt_pk_bf16(qf_hi[2 * m], qf_hi[2 * m + 1]);
    }

    for (int mt = wv; mt < 13; mt += 4) {
        const int t = mt * 16 + li;
        const int tld = (t < TT) ? t : TT - 1;
        const unsigned short* hp = seq_hb + ((size_t)b * TT + tld) * 64 + lg * 8;
        short8 h8l = *(const short8*)hp;
        short8 h8h = *(const short8*)(hp + 32);

        U8 d8l, d8h, m8l, m8h;
#pragma unroll
        for (int m = 0; m < 4; ++m) {
            float h0, h1, d0, d1, p0, p1;
            h0 = bf2f((unsigned short)h8l[2 * m]); h1 = bf2f((unsigned short)h8l[2 * m + 1]);
            d0 = qf_lo[2 * m] - h0; d1 = qf_lo[2 * m + 1] - h1;
            p0 = qf_lo[2 * m] * h0; p1 = qf_lo[2 * m + 1] * h1;
            d8l.u[m] = cvt_pk_bf16(d0, d1);
            m8l.u[m] = cvt_pk_bf16(p0, p1);
            h0 = bf2f((unsigned short)h8h[2 * m]); h1 = bf2f((unsigned short)h8h[2 * m + 1]);
            d0 = qf_hi[2 * m] - h0; d1 = qf_hi[2 * m + 1] - h1;
            p0 = qf_hi[2 * m] * h0; p1 = qf_hi[2 * m + 1] * h1;
            d8h.u[m] = cvt_pk_bf16(d0, d1);
            m8h.u[m] = cvt_pk_bf16(p0, p1);
        }

        f32x4 acc[4];
#pragma unroll
        for (int nt = 0; nt < 4; ++nt) acc[nt] = (f32x4){0.f, 0.f, 0.f, 0.f};
#pragma unroll
        for (int nt = 0; nt < 4; ++nt) {
            acc[nt] = __builtin_amdgcn_mfma_f32_16x16x32_bf16(q8l.s8, w1r[0][nt], acc[nt], 0, 0, 0);
            acc[nt] = __builtin_amdgcn_mfma_f32_16x16x32_bf16(q8h.s8, w1r[1][nt], acc[nt], 0, 0, 0);
            acc[nt] = __builtin_amdgcn_mfma_f32_16x16x32_bf16(h8l,    w1r[2][nt], acc[nt], 0, 0, 0);
            acc[nt] = __builtin_amdgcn_mfma_f32_16x16x32_bf16(h8h,    w1r[3][nt], acc[nt], 0, 0, 0);
            acc[nt] = __builtin_amdgcn_mfma_f32_16x16x32_bf16(d8l.s8, w1r[4][nt], acc[nt], 0, 0, 0);
            acc[nt] = __builtin_amdgcn_mfma_f32_16x16x32_bf16(d8h.s8, w1r[5][nt], acc[nt], 0, 0, 0);
            acc[nt] = __builtin_amdgcn_mfma_f32_16x16x32_bf16(m8l.s8, w1r[6][nt], acc[nt], 0, 0, 0);
            acc[nt] = __builtin_amdgcn_mfma_f32_16x16x32_bf16(m8h.s8, w1r[7][nt], acc[nt], 0, 0, 0);
        }

#pragma unroll
        for (int nt = 0; nt < 4; ++nt)
#pragma unroll
            for (int jj = 0; jj < 4; ++jj) {
                float v = acc[nt][jj] + b1v[nt];
                a1s[wv][lg * 4 + jj][nt * 16 + li] = (v > 0.f) ? v : 0.25f * v;
            }

        const float* arow = &a1s[wv][li][0];
        f32x4 acc2 = (f32x4){0.f, 0.f, 0.f, 0.f};
#pragma unroll
        for (int c2 = 0; c2 < 2; ++c2) {
            f32x4 v0 = *(const f32x4*)(arow + c2 * 32 + lg * 8);
            f32x4 v1 = *(const f32x4*)(arow + c2 * 32 + lg * 8 + 4);
            U8 a2f;
            a2f.u[0] = cvt_pk_bf16(v0[0], v0[1]);
            a2f.u[1] = cvt_pk_bf16(v0[2], v0[3]);
            a2f.u[2] = cvt_pk_bf16(v1[0], v1[1]);
            a2f.u[3] = cvt_pk_bf16(v1[2], v1[3]);
            acc2 = __builtin_amdgcn_mfma_f32_16x16x32_bf16(a2f.s8, w2r[c2], acc2, 0, 0, 0);
        }

#pragma unroll
        for (int jj = 0; jj < 4; ++jj) {
            float a2 = acc2[jj] + b2v;
            a2 = (a2 > 0.f) ? a2 : 0.25f * a2;
            float part = a2 * w3v;
            part += __shfl_xor(part, 1);
            part += __shfl_xor(part, 2);
            part += __shfl_xor(part, 4);
            part += __shfl_xor(part, 8);
            int tt = mt * 16 + lg * 4 + jj;
            if (li == 0 && tt < TT)
                logit_lds[tt] = (tt < len) ? (part + b3r) : -1e9f;
        }
    }
    __syncthreads();

    float v = (tid < TT) ? logit_lds[tid] : -1e30f;
    float m = v;
#pragma unroll
    for (int s = 1; s < 64; s <<= 1) m = fmaxf(m, __shfl_xor(m, s));
    if (l == 0) red[wv] = m;
    __syncthreads();
    m = fmaxf(fmaxf(red[0], red[1]), fmaxf(red[2], red[3]));
    float e = (tid < TT) ? __expf(v - m) : 0.f;
    float sum = e;
#pragma unroll
    for (int s = 1; s < 64; s <<= 1) sum += __shfl_xor(sum, s);
    if (l == 0) red[4 + wv] = sum;
    __syncthreads();
    float inv = __fdividef(1.f, red[4] + red[5] + red[6] + red[7]);
    if (tid < TT) scores[(size_t)b * TT + tid] = e * inv;
}

// ---------------------------------------------------------------------------
// FFN chain (tiny, unchanged)
// ---------------------------------------------------------------------------
__global__ __launch_bounds__(256) void k_fc1(const float* __restrict__ fin,
                                             const float* __restrict__ tgt,
                                             const float* __restrict__ oth,
                                             const float* __restrict__ Wt,
                                             const float* __restrict__ bvec,
                                             float* __restrict__ fout) {
    __shared__ float z0[164];
    int b = blockIdx.x, tid = threadIdx.x;
    if (tid < 64) z0[tid] = fin[b * 64 + tid];
    else if (tid < 128) z0[tid] = tgt[b * 64 + tid - 64];
    else if (tid < 164) z0[tid] = oth[b * 36 + tid - 128];
    __syncthreads();
    float acc = bvec[tid];
#pragma unroll 4
    for (int k = 0; k < 164; ++k) acc += z0[k] * Wt[k * 256 + tid];
    fout[(size_t)b * 256 + tid] = acc;
}

template <int F>
__global__ __launch_bounds__(256) void k_stats(const float* __restrict__ x, float* __restrict__ stat) {
    int c = blockIdx.x, tid = threadIdx.x;
    float s = 0.f, sq = 0.f;
    for (int i = tid; i < BB; i += 256) {
        float v = x[(size_t)i * F + c];
        s += v; sq += v * v;
    }
#pragma unroll
    for (int m = 1; m < 64; m <<= 1) { s += __shfl_xor(s, m); sq += __shfl_xor(sq, m); }
    __shared__ float rs[4], rq[4];
    if ((tid & 63) == 0) { rs[tid >> 6] = s; rq[tid >> 6] = sq; }
    __syncthreads();
    if (tid == 0) {
        float S = rs[0] + rs[1] + rs[2] + rs[3];
        float Q = rq[0] + rq[1] + rq[2] + rq[3];
        float mean = S * (1.f / BB);
        float var = Q * (1.f / BB) - mean * mean;
        stat[c] = mean;
        stat[F + c] = var;
    }
}

__global__ __launch_bounds__(256) void k_fc2(const float* __restrict__ f1,
                                             const float* __restrict__ st1,
                                             const float* __restrict__ Wt,
                                             const float* __restrict__ bvec,
                                             float* __restrict__ f2) {
    __shared__ float z[256];
    int b = blockIdx.x, tid = threadIdx.x;
    float x = f1[(size_t)b * 256 + tid];
    z[tid] = dicef_(x, st1[tid], st1[256 + tid]);
    __syncthreads();
    if (tid < 128) {
        float acc = bvec[tid];
#pragma unroll 4
        for (int k = 0; k < 256; ++k) acc += z[k] * Wt[k * 128 + tid];
        f2[(size_t)b * 128 + tid] = acc;
    }
}

__global__ __launch_bounds__(128) void k_fc3(const float* __restrict__ f2,
                                             const float* __restrict__ st2,
                                             const float* __restrict__ Wt,
                                             const float* __restrict__ bvec,
                                             float* __restrict__ f3) {
    __shared__ float z[128];
    int b = blockIdx.x, tid = threadIdx.x;
    float x = f2[(size_t)b * 128 + tid];
    z[tid] = dicef_(x, st2[tid], st2[128 + tid]);
    __syncthreads();
    if (tid < 64) {
        float acc = bvec[tid];
#pragma unroll 4
        for (int k = 0; k < 128; ++k) acc += z[k] * Wt[k * 64 + tid];
        f3[(size_t)b * 64 + tid] = acc;
    }
}

__global__ void k_out(const float* __restrict__ f3, const float* __restrict__ st3,
                      const float* __restrict__ outW, const float* __restrict__ outb,
                      float* __restrict__ out) {
    int b = blockIdx.x, l = threadIdx.x;  // 64 threads
    float x = f3[(size_t)b * 64 + l];
    float z = dicef_(x, st3[l], st3[64 + l]);
    float p = z * outW[l];
#pragma unroll
    for (int m = 1; m < 64; m <<= 1) p += __shfl_xor(p, m);
    if (l == 0) out[b] = sigmoidf_(p + outb[0]);
}

// ---------------------------------------------------------------------------
extern "C" void kernel_launch(void* const* d_in, const int* in_sizes, int n_in,
                              void* d_out, int out_size, void* d_ws, size_t ws_size,
                              hipStream_t stream) {
    const float* dense      = (const float*)d_in[0];
    const int*   sparse     = (const int*)d_in[1];
    const int*   seq_idx    = (const int*)d_in[2];
    const int*   item_idx   = (const int*)d_in[3];
    const int*   hist_len   = (const int*)d_in[4];
    const float* item_table = (const float*)d_in[5];
    const float* other_tab  = (const float*)d_in[6];
    const float* gru_W = (const float*)d_in[7];
    const float* gru_U = (const float*)d_in[8];
    const float* gru_b = (const float*)d_in[9];
    const float* aug_W = (const float*)d_in[10];
    const float* aug_U = (const float*)d_in[11];
    const float* aug_b = (const float*)d_in[12];
    const float* att_W1 = (const float*)d_in[13];
    const float* att_b1 = (const float*)d_in[14];
    const float* att_W2 = (const float*)d_in[15];
    const float* att_b2 = (const float*)d_in[16];
    const float* att_W3 = (const float*)d_in[17];
    const float* att_b3 = (const float*)d_in[18];
    const float* ffn_W1 = (const float*)d_in[19];
    const float* ffn_b1 = (const float*)d_in[20];
    const float* ffn_W2 = (const float*)d_in[21];
    const float* ffn_b2 = (const float*)d_in[22];
    const float* ffn_W3 = (const float*)d_in[23];
    const float* ffn_b3 = (const float*)d_in[24];
    const float* out_W  = (const float*)d_in[25];
    const float* out_b  = (const float*)d_in[26];

    float* wsf = (float*)d_ws;
    unsigned short* xwb   = (unsigned short*)(wsf);              // (B*T,192) bf16
    unsigned short* seqhb = (unsigned short*)(wsf + 19660800);   // (B,T,64) bf16
    float* scores = wsf + 26214400;            // B*T
    float* target = wsf + 26419200;            // B*64
    float* other  = wsf + 26484736;            // B*36
    float* finals = wsf + 26521600;            // B*64
    float* f1     = wsf + 26587136;            // B*256
    float* f2     = wsf + 26849280;            // B*128
    float* f3     = wsf + 26980352;            // B*64
    float* st1    = wsf + 27045888;            // 512
    float* st2    = wsf + 27046400;            // 256
    float* st3    = wsf + 27046656;            // 128

    float* dout = (float*)d_out;
    const int Mtiles = (BB * TT) / 16;  // 12800

    k_prep<<<BB, 64, 0, stream>>>(dense, sparse, item_idx, item_table, other_tab, target, other);

    // xw1 = gather(item_table, seq_idx) @ gru_W + gru_b  (bf16 MFMA)
    k_xw<1><<<800, 256, 0, stream>>>(seq_idx, item_table, nullptr, gru_W, gru_b, xwb, Mtiles, 3200);

    // GRU1 recurrence -> seq_h bf16 (B,T,64)
    k_scan3<0><<<BB, 256, 0, stream>>>(xwb, gru_U, hist_len, scores, seqhb, finals);

    // attention MLP (MFMA) + fused softmax -> scores
    k_att<<<BB, 256, 0, stream>>>(target, seqhb, att_W1, att_b1, att_W2, att_b2,
                                  att_W3, att_b3, hist_len, scores);

    // xw2 = seq_h @ aug_W + aug_b  (bf16 MFMA, reuses xw buffer)
    k_xw<0><<<800, 256, 0, stream>>>(nullptr, nullptr, seqhb, aug_W, aug_b, xwb, Mtiles, 3200);

    // AUGRU recurrence -> finals f32 (B,64)
    k_scan3<1><<<BB, 256, 0, stream>>>(xwb, aug_U, hist_len, scores, seqhb, finals);

    k_fc1<<<BB, 256, 0, stream>>>(finals, target, other, ffn_W1, ffn_b1, f1);
    k_stats<256><<<256, 256, 0, stream>>>(f1, st1);
    k_fc2<<<BB, 256, 0, stream>>>(f1, st1, ffn_W2, ffn_b2, f2);
    k_stats<128><<<128, 256, 0, stream>>>(f2, st2);
    k_fc3<<<BB, 128, 0, stream>>>(f2, st2, ffn_W3, ffn_b3, f3);
    k_stats<64><<<64, 256, 0, stream>>>(f3, st3);
    k_out<<<BB, 64, 0, stream>>>(f3, st3, out_W, out_b, dout);
}